// Round 8
// baseline (357.712 us; speedup 1.0000x reference)
//
#include <hip/hip_runtime.h>
#include <stdint.h>

#define BS 16
#define NP 25200
#define NC 80
#define DIM 85
#define KN 2048
#define CAP 4096
#define BINS 512
#define MAXD 300
#define SBLK 99    // score blocks per batch (256 boxes each; 99*256=25344)
#define QCAP 128

// ---------------------------------------------------------------- score + hist
// R6 kernel verbatim (passed bit-exact). obj-gate: 75% of rows never touch
// their 80 class floats -> ~55-60% of input lines fetched. 1 thread = 1 box,
// no staging, no barriers on the load path.
__global__ __launch_bounds__(256) void score_hist_kernel(const float* __restrict__ preds,
        float* __restrict__ score, int* __restrict__ clsout, int* __restrict__ hpart) {
    int b = blockIdx.x / SBLK;
    int chunk = blockIdx.x % SBLK;
    int tid = threadIdx.x;
    __shared__ int h[BINS];
    h[tid] = 0; h[tid + 256] = 0;
    __syncthreads();
    int n = chunk * 256 + tid;
    if (n < NP) {
        const float* bp = preds + ((size_t)b * NP + n) * DIM;
        float obj = bp[4];
        float sc = -1.0f; int bidx = 0;
        if (obj > 0.25f) {
            float best = -1.0f;
            #pragma unroll
            for (int kk = 0; kk < 10; ++kk) {
                float v[8];
                #pragma unroll
                for (int j = 0; j < 8; ++j) v[j] = bp[5 + kk * 8 + j];
                #pragma unroll
                for (int j = 0; j < 8; ++j) {
                    float s = v[j] * obj;                  // same expr/order as R5
                    if (s > best) { best = s; bidx = kk * 8 + j; }  // strict >
                }
            }
            if (best > 0.25f) sc = best;
        }
        int gi = b * NP + n;
        score[gi] = sc;
        clsout[gi] = bidx;
        if (sc > 0.0f) {
            int bin = (int)(__float_as_uint(sc) >> 15) - 0x7D00;
            bin = max(0, min(BINS - 1, bin));
            atomicAdd(&h[bin], 1);
        }
    }
    __syncthreads();
    int* hp = hpart + ((size_t)(b * SBLK + chunk)) * BINS;
    hp[tid] = h[tid];
    hp[tid + 256] = h[tid + 256];
}

// ---------------------------------------------------------------- in-wave bitonic
template<int V, bool DESC, typename T>
__device__ inline void wave_bitonic(T (&v)[V], int lane) {
    const int N = V * 64;
    #pragma unroll
    for (int k = 2; k <= N; k <<= 1) {
        #pragma unroll
        for (int j = N >> 1; j > 0; j >>= 1) {
            if (j >= k) continue;          // strides start at k/2
            if (j >= 64) {
                int dv = j >> 6;
                #pragma unroll
                for (int a = 0; a < V; ++a) {
                    int p = a ^ dv;
                    if (a < p) {
                        int e = a * 64;    // k >= 128 here: lane bits can't hit k
                        bool kml = (((e & k) == 0) == DESC);
                        T lo = v[a], hi = v[p];
                        T mx = lo > hi ? lo : hi;
                        T mn = lo > hi ? hi : lo;
                        v[a] = kml ? mx : mn;
                        v[p] = kml ? mn : mx;
                    }
                }
            } else {
                #pragma unroll
                for (int a = 0; a < V; ++a) {
                    int e = a * 64 + lane;
                    T pv = __shfl_xor(v[a], j);
                    bool isLower = (lane & j) == 0;
                    bool kml = (((e & k) == 0) == DESC);
                    bool takeMax = (kml == isLower);
                    T mx = v[a] > pv ? v[a] : pv;
                    T mn = v[a] > pv ? pv : v[a];
                    v[a] = takeMax ? mx : mn;
                }
            }
        }
    }
}

// ---------------------------------------------------------------- fused tail
// ONE kernel, 16 blocks x 1024 threads; everything after the hist-reduce is
// batch-local so all state lives in LDS (~80 KB): reduce partials ->
// threshold (verbatim scan) -> scatter (LDS counters) -> per-bin in-register
// sort + candidate build -> per-class ballot NMS (5 classes/wave, private
// LDS queues) -> prefix + output (all 300 rows written; no d_out memset).
// Phase math verbatim R7's thresh/scatter/binsort/nms/out kernels.
__global__ __launch_bounds__(1024) void tail_kernel(const float* __restrict__ score,
        const float* __restrict__ preds, const int* __restrict__ cls,
        const int* __restrict__ hpart, float* __restrict__ out) {
    int b = blockIdx.x;
    int tid = threadIdx.x;
    int lane = tid & 63;
    int wid = tid >> 6;

    __shared__ unsigned long long k[CAP];     // 32 KB
    __shared__ float4 bx4[KN];                // 32 KB
    __shared__ unsigned char carr[KN];        // 2 KB
    __shared__ unsigned char keep[KN];        // 2 KB
    __shared__ unsigned short q[16][QCAP];    // 4 KB
    __shared__ int h[BINS];                   // 2 KB
    __shared__ int bstartA[BINS];             // 2 KB
    __shared__ int bcnt[BINS];                // 2 KB
    __shared__ int sT, sMb, sKept;

    // ---- reduce SBLK partial hists
    if (tid < BINS) {
        int s = 0;
        const int* hp = hpart + (size_t)b * SBLK * BINS + tid;
        for (int c = 0; c < SBLK; ++c) s += hp[c * BINS];
        h[tid] = s;
        bcnt[tid] = 0;
    }
    for (int r = tid; r < KN; r += 1024) { carr[r] = 0xFF; keep[r] = 0; }
    __syncthreads();
    // ---- threshold + bin starts (wave 0), verbatim
    if (tid < 64) {
        int base = lane * 8;
        int v[8]; int ssum = 0;
        #pragma unroll
        for (int kk = 0; kk < 8; ++kk) { v[kk] = h[base + kk]; ssum += v[kk]; }
        int x = ssum;
        #pragma unroll
        for (int off = 1; off < 64; off <<= 1) {
            int y = __shfl_down(x, off);
            if (lane + off < 64) x += y;
        }
        int run = x - ssum;                    // suffix over bins > base+7
        int cand = -1;
        #pragma unroll
        for (int kk = 7; kk >= 0; --kk) {
            bstartA[base + kk] = run;          // exclusive (bins strictly above)
            run += v[kk];
            if (run >= KN && cand < 0) cand = base + kk;
        }
        #pragma unroll
        for (int off = 1; off < 64; off <<= 1) cand = max(cand, __shfl_xor(cand, off));
        if (lane == 0) sT = max(cand, 0);
    }
    __syncthreads();
    if (tid == 0) {
        int T = sT;
        int n = min(bstartA[T] + h[T], CAP);
        sMb = min(n, KN);
    }
    __syncthreads();
    int T = sT;
    int Mb = sMb;
    // ---- scatter qualifying scores into k[] (LDS counters; order within a
    //      bin is nondeterministic, erased by the full-key bin sort below)
    const float* sb = score + (size_t)b * NP;
    for (int i = tid; i < NP; i += 1024) {
        float sc = sb[i];
        if (sc > 0.0f) {
            int bin = (int)(__float_as_uint(sc) >> 15) - 0x7D00;
            bin = max(0, min(BINS - 1, bin));
            if (bin >= T) {
                int pos = bstartA[bin] + atomicAdd(&bcnt[bin], 1);
                if (pos < CAP) {
                    unsigned int ii = (unsigned int)i;
                    k[pos] = ((unsigned long long)__float_as_uint(sc) << 32)
                           | (unsigned int)(~ii);
                }
            }
        }
    }
    __syncthreads();
    // ---- per-bin descending sort + candidate build (wave w: bins T+w, +16, ...)
    for (int bin = T + wid; bin < BINS; bin += 16) {
        int cnt = h[bin];
        if (cnt <= 0) continue;
        int bs = bstartA[bin];
        if (bs >= Mb) continue;                // entirely beyond the top-KN cut
        unsigned long long v[4];
        #pragma unroll
        for (int a = 0; a < 4; ++a) {
            int idx = a * 64 + lane;
            v[a] = (idx < cnt && bs + idx < CAP) ? k[bs + idx] : 0ull;
        }
        wave_bitonic<4, true>(v, lane);
        #pragma unroll
        for (int a = 0; a < 4; ++a) {
            int idx = a * 64 + lane;
            if (idx < cnt && bs + idx < CAP) k[bs + idx] = v[a];
        }
        #pragma unroll
        for (int a = 0; a < 4; ++a) {
            int idx = a * 64 + lane;
            int r = bs + idx;
            if (idx < cnt && r < Mb) {
                unsigned long long key = v[a];
                unsigned int i = ~(unsigned int)key;
                const float* p = preds + ((size_t)b * NP + i) * DIM;
                float x = p[0], y = p[1], w = p[2], hh = p[3];
                bx4[r] = make_float4(x - w * 0.5f, y - hh * 0.5f,
                                     x + w * 0.5f, y + hh * 0.5f);
                carr[r] = (unsigned char)cls[(size_t)b * NP + i];
            }
        }
    }
    __syncthreads();
    // ---- per-class ballot NMS (wave w: classes w, w+16, ..., w+64)
    #pragma unroll
    for (int t5 = 0; t5 < 5; ++t5) {
        int c = wid + 16 * t5;
        unsigned short* qw = q[wid];
        int base = 0;
        for (int r0 = 0; r0 < Mb; r0 += 64) {
            int r = r0 + lane;
            bool mine = (r < Mb) && (carr[r] == (unsigned char)c);
            unsigned long long m = __ballot(mine);
            int pos = base + (int)__popcll(m & ((1ull << lane) - 1ull));
            if (mine && pos < QCAP) qw[pos] = (unsigned short)r;
            base += (int)__popcll(m);
        }
        int nc = min(base, QCAP);
        if (nc <= 0) continue;
        int ord0 = (lane < nc) ? (int)qw[lane] : 0;
        int ord1 = (lane + 64 < nc) ? (int)qw[64 + lane] : 0;
        float4 A0 = (lane < nc) ? bx4[ord0] : make_float4(0.f, 0.f, 0.f, 0.f);
        float4 A1 = (lane + 64 < nc) ? bx4[ord1] : make_float4(0.f, 0.f, 0.f, 0.f);
        float off = (float)c * 7680.0f;
        A0.x += off; A0.y += off; A0.z += off; A0.w += off;
        A1.x += off; A1.y += off; A1.z += off; A1.w += off;
        float ar0 = (A0.z - A0.x) * (A0.w - A0.y);
        float ar1 = (A1.z - A1.x) * (A1.w - A1.y);
        unsigned long long sup0 = 0, sup1 = 0, keep0 = 0, keep1 = 0;
        for (int idx = 0; idx < nc; ++idx) {
            bool hi = idx >= 64;
            int bit = idx & 63;
            unsigned long long s = hi ? sup1 : sup0;   // wave-uniform
            if ((s >> bit) & 1ull) continue;           // uniform branch
            if (hi) keep1 |= 1ull << bit; else keep0 |= 1ull << bit;
            float bx_ = hi ? __shfl(A1.x, bit) : __shfl(A0.x, bit);
            float by_ = hi ? __shfl(A1.y, bit) : __shfl(A0.y, bit);
            float bz_ = hi ? __shfl(A1.z, bit) : __shfl(A0.z, bit);
            float bw_ = hi ? __shfl(A1.w, bit) : __shfl(A0.w, bit);
            float ba_ = hi ? __shfl(ar1, bit) : __shfl(ar0, bit);
            bool s0, s1;
            {
                float lx = fmaxf(bx_, A0.x), ly = fmaxf(by_, A0.y);
                float rx = fminf(bz_, A0.z), ry = fminf(bw_, A0.w);
                float iw = fmaxf(rx - lx, 0.0f), ih = fmaxf(ry - ly, 0.0f);
                float inter = iw * ih;
                float iou = inter / (ba_ + ar0 - inter + 1e-7f);  // a_i + a_j order = ref
                s0 = (lane > idx) && (lane < nc) && (iou > 0.45f);
            }
            {
                float lx = fmaxf(bx_, A1.x), ly = fmaxf(by_, A1.y);
                float rx = fminf(bz_, A1.z), ry = fminf(bw_, A1.w);
                float iw = fmaxf(rx - lx, 0.0f), ih = fmaxf(ry - ly, 0.0f);
                float inter = iw * ih;
                float iou = inter / (ba_ + ar1 - inter + 1e-7f);
                s1 = ((64 + lane) > idx) && ((64 + lane) < nc) && (iou > 0.45f);
            }
            sup0 |= __ballot(s0);
            sup1 |= __ballot(s1);
        }
        // classes are disjoint in r -> no write races across waves
        if (lane < nc && ((keep0 >> lane) & 1ull)) keep[ord0] = 1;
        if (lane + 64 < nc && ((keep1 >> lane) & 1ull)) keep[ord1] = 1;
    }
    __syncthreads();
    // ---- output: wave 0 prefix + write kept rows (global rank order)
    if (tid < 64) {
        int running = 0;
        for (int ch = 0; ch < 32; ++ch) {
            int r = ch * 64 + lane;
            bool kp = keep[r] != 0;
            unsigned long long m = __ballot(kp);
            int pos = running + (int)__popcll(m & ((1ull << lane) - 1ull));
            if (kp && pos < MAXD) {
                float4 bx = bx4[r];
                float sc = __uint_as_float((unsigned int)(k[r] >> 32));
                float* o = out + ((size_t)b * MAXD + pos) * 6;
                o[0] = bx.x * 3.0f;      // 1920/640
                o[1] = bx.y * 1.6875f;   // 1080/640
                o[2] = bx.z * 3.0f;
                o[3] = bx.w * 1.6875f;
                o[4] = sc;
                o[5] = (float)carr[r];
            }
            running += (int)__popcll(m);
        }
        if (tid == 0) sKept = min(running, MAXD);
    }
    __syncthreads();
    // ---- zero-fill rows [kept, MAXD) (replaces the d_out memset)
    int kept = sKept;
    int ztot = (MAXD - kept) * 6;
    float* zbase = out + ((size_t)b * MAXD + kept) * 6;
    for (int z = tid; z < ztot; z += 1024) zbase[z] = 0.0f;
}

// ---------------------------------------------------------------- launch
extern "C" void kernel_launch(void* const* d_in, const int* in_sizes, int n_in,
                              void* d_out, int out_size, void* d_ws, size_t ws_size,
                              hipStream_t stream) {
    const float* preds = (const float*)d_in[0];
    float* out = (float*)d_out;
    char* ws = (char*)d_ws;
    size_t off = 0;
    auto alloc = [&](size_t bytes) -> void* {
        void* p = ws + off;
        off += (bytes + 255) & ~(size_t)255;
        return p;
    };
    float* score = (float*)alloc((size_t)BS * NP * 4);
    int* cls    = (int*)alloc((size_t)BS * NP * 4);
    int* hpart  = (int*)alloc((size_t)BS * SBLK * BINS * 4);   // 3.2 MB
    if (ws_size < off) return;

    score_hist_kernel<<<BS * SBLK, 256, 0, stream>>>(preds, score, cls, hpart);
    tail_kernel<<<BS, 1024, 0, stream>>>(score, preds, cls, hpart, out);
}